// Round 8
// baseline (20.012 us; speedup 1.0000x reference)
//
#include <hip/hip_runtime.h>

// Problem constants (match reference)
#define NS (1 << 20)          // samples per segment
#define THREADS 256
#define TABN 4096             // interp cells per segment (nodes 0..TABN)
#define TABSTRIDE 4160        // floats per segment table slot (float4-aligned)

// build kernel: 64 nodes per block, 4-way j-split per node
#define BNODES 64
#define BBPS 65               // ceil((TABN+1)/BNODES)
#define BGRID (4 * BBPS)      // 260

// eval kernel geometry
#define MILP 32
#define MSPB (THREADS * MILP)             // 8192 samples per block
#define MBPS (NS / MSPB)                  // 128 blocks per seg
#define MGRID (4 * MBPS)                  // 512

// hierarchical fence-free reduce: 8 groups of 64 blocks
#define RGROUPS 8
#define GSIZE (MGRID / RGROUPS)           // 64
#define CNT1_BITS 7                       // count field for 64 arrivals
#define CNT2_BITS 4                       // count field for 8 arrivals

// fallback (direct) kernel geometry
#define FILP 8
#define FSPB (THREADS * FILP)
#define FBPS (NS / FSPB)                  // 512
#define FGRID (4 * FBPS)                  // 2048

#define SCALE 262144.0        // 2^18 fixed-point scale for deterministic i64 reduce
#define TAB_BYTES ((size_t)(4 * TABSTRIDE * sizeof(float)))
#define WS_NEED (256 + TAB_BYTES)

typedef float v2f __attribute__((ext_vector_type(2)));

// Per-segment parameterization (validated on HW rounds 1/3/4/5/6/7, absmax 0.0):
// seg 0: u_y1  (jump_y, +1): val = 3*dphi1 - 5*corr
// seg 1: u_ym1 (jump_y, -1): val = 1*dphi1 - 5*corr
// seg 2: u_x1  (jump_x, +1): val = 1*dphi1 - 3*corr
// seg 3: u_xm1 (jump_x, -1): val = -1*dphi1 - 7*corr

// ---------------- table build: G_seg at nodes i/TABN, i in [0, TABN] ----------------
__global__ __launch_bounds__(THREADS) void build_tab(
    const float* __restrict__ sW1, const float* __restrict__ sb1,
    const float* __restrict__ sW2, const float* __restrict__ sb2,
    const float* __restrict__ jW1, const float* __restrict__ jb1,
    const float* __restrict__ jW2, const float* __restrict__ jb2,
    float* __restrict__ tab, unsigned long long* __restrict__ ctrs)
{
    __shared__ __align__(16) float s_w[64][12];
    __shared__ float s_swv[2];

    const int bid = blockIdx.x;
    const int seg = bid / BBPS;
    const int blk = bid - seg * BBPS;
    const int tid = threadIdx.x;

    // Zero the reduce counters with AGENT-scope atomic stores (land at the
    // coherence point, so eval's memory-side atomic RMWs see them; a plain
    // store could sit dirty in this XCD's L2 and be missed).
    if (bid == 0 && tid < 1 + RGROUPS)
        __hip_atomic_store(&ctrs[tid], 0ull, __ATOMIC_RELAXED, __HIP_MEMORY_SCOPE_AGENT);

    const int ca  = (seg < 2) ? 0 : 1;
    const int pp  = 1 - ca;
    const int kv  = (seg < 2) ? 2 : 1;
    const int kd2 = 3 - kv;
    const float sign  = (seg & 1) ? -1.0f : 1.0f;
    const float alpha = (seg == 0) ? 3.0f : ((seg == 3) ? -1.0f : 1.0f);
    const float beta  = (seg <  2) ? -5.0f : ((seg == 2) ? -3.0f : -7.0f);
    const float TL = 2.885390081777927f;             // 2*log2(e)

    if (tid < 64) {
        const int j = tid;
        float sw1c = sW1[ca * 64 + j], jw1c = jW1[ca * 64 + j];
        float sw1p = sW1[pp * 64 + j], jw1p = jW1[pp * 64 + j];
        s_w[j][0] = sw1c * TL * sign;                // pre = wc*u + bb (sign folded)
        s_w[j][1] = jw1c * TL * sign;
        s_w[j][2] = sb1[j] * TL;
        s_w[j][3] = jb1[j] * TL;
        s_w[j][4] = 4.0f * sw1p * sW2[j * 3 + 0];    // x4: tp = t/4
        s_w[j][5] = 4.0f * jw1p * jW2[j * 3 + 0];
        s_w[j][6] = 4.0f * sw1p * sW2[j * 3 + kd2];
        s_w[j][7] = 4.0f * jw1p * jW2[j * 3 + kd2];
        s_w[j][8] = sW2[j * 3 + kv];
        s_w[j][9] = jW2[j * 3 + kv];
    }
    __syncthreads();
    if (tid < 2) {
        float s = 0.0f;
        for (int j = 0; j < 64; ++j) s += s_w[j][8 + tid];
        s_swv[tid] = s + (tid ? jb2[kv] : sb2[kv]);  // V = swv - 2*sum(g*wv)
    }
    __syncthreads();

    // 4 threads per node: part p handles j in [16p, 16p+16)
    const int part = tid & 3;
    const int node = blk * BNODES + (tid >> 2);
    const float u = (float)node * (1.0f / TABN);

    float Vgs = 0.0f, D0s = 0.0f, D2s = 0.0f, Vgj = 0.0f, D0j = 0.0f, D2j = 0.0f;
    #pragma unroll 4
    for (int jj = 0; jj < 16; ++jj) {
        const int j = (part << 4) | jj;
        const float4 A = *(const float4*)&s_w[j][0];
        const float4 B = *(const float4*)&s_w[j][4];
        const v2f   wv = *(const v2f*)&s_w[j][8];
        float ps = fmaf(A.x, u, A.z);
        float Es = __builtin_amdgcn_exp2f(ps);
        float gs = __builtin_amdgcn_rcpf(Es + 1.0f);
        float ts = fmaf(-gs, gs, gs);
        Vgs = fmaf(gs, wv.x, Vgs);
        D0s = fmaf(ts, B.x, D0s);
        D2s = fmaf(ts, B.z, D2s);
        float pj = fmaf(A.y, u, A.w);
        float Ej = __builtin_amdgcn_exp2f(pj);
        float gj = __builtin_amdgcn_rcpf(Ej + 1.0f);
        float tj = fmaf(-gj, gj, gj);
        Vgj = fmaf(gj, wv.y, Vgj);
        D0j = fmaf(tj, B.y, D0j);
        D2j = fmaf(tj, B.w, D2j);
    }
    // combine the 4 j-parts (lanes 4k..4k+3 hold the same node)
    #pragma unroll
    for (int m = 1; m <= 2; m <<= 1) {
        Vgs += __shfl_xor(Vgs, m); D0s += __shfl_xor(D0s, m); D2s += __shfl_xor(D2s, m);
        Vgj += __shfl_xor(Vgj, m); D0j += __shfl_xor(D0j, m); D2j += __shfl_xor(D2j, m);
    }

    float r = __builtin_amdgcn_sqrtf(fmaf(u, u, 1e-12f));
    float inv_r = __builtin_amdgcn_rcpf(r);
    float rcb = fmaxf(fmaf(-2.0f, r, 1.0f), 0.0f);   // max(1 - r/0.5, 0)
    float rc = rcb * rcb;
    float rl = __builtin_amdgcn_exp2f(0.66666666666666663f * __builtin_amdgcn_logf(r));
    float rcrl = rc * rl;                            // rc * r^(2/3)
    float rcrlm1 = rcrl * inv_r;                     // rc * r^(2/3 - 1)
    float q = u * inv_r;
    float bcv = fmaf(-u, u, 1.0f);
    float wgt = fminf(40.0f * u, 1.0f);
    float VS = fmaf(-2.0f, Vgs, s_swv[0]);
    float VJ = fmaf(-2.0f, Vgj, s_swv[1]);
    float dphi1 = fmaf(D2s, q, D0s) * rcrl + bcv * fmaf(D2j, u, D0j);
    float corr = VJ * bcv + VS * rcrlm1;
    float val = fmaf(alpha, dphi1, beta * corr);
    float G = val * val * wgt;                       // >= 0 always

    if (part == 0 && node <= TABN) tab[seg * TABSTRIDE + node] = G;
}

// ---------------- main: LDS table + interp + hierarchical fence-free reduce ----------------
__global__ __launch_bounds__(THREADS) void eval_main(
    const float* __restrict__ u0p, const float* __restrict__ u1p,
    const float* __restrict__ u2p, const float* __restrict__ u3p,
    const float* __restrict__ tab, unsigned long long* __restrict__ ctrs,
    float* __restrict__ out)
{
    __shared__ __align__(16) float s_tab[TABN + 4];   // 16.4 KiB
    __shared__ float s_red[THREADS / 64];

    const int bid = blockIdx.x;
    const int seg = bid >> 7;                      // MBPS = 128
    const int chunk = bid & 127;
    const int tid = threadIdx.x;

    // stage this segment's table (4096 floats as float4 + boundary node 4096)
    {
        const float4* src = (const float4*)(tab + seg * TABSTRIDE);
        float4* dst = (float4*)s_tab;
        #pragma unroll
        for (int t = 0; t < 4; ++t)
            dst[t * THREADS + tid] = src[t * THREADS + tid];
        if (tid == 0) s_tab[TABN] = tab[seg * TABSTRIDE + TABN];
    }
    __syncthreads();

    const float* up = (seg == 0) ? u0p : (seg == 1) ? u1p : (seg == 2) ? u2p : u3p;
    const float4* up4 = (const float4*)up;

    float acc = 0.0f;
    #pragma unroll
    for (int t = 0; t < MILP / 4; ++t) {
        float4 u4 = up4[chunk * (MSPB / 4) + t * THREADS + tid];
        float us[4] = {u4.x, u4.y, u4.z, u4.w};
        #pragma unroll
        for (int s = 0; s < 4; ++s) {
            float fidx = us[s] * (float)TABN;
            int i = (int)fidx;
            i = (i < TABN - 1) ? i : (TABN - 1);
            float f = fidx - (float)i;
            float T0 = s_tab[i];          // pair compiles to ds_read2_b32
            float T1 = s_tab[i + 1];
            acc += fmaf(f, T1 - T0, T0);
        }
    }

    #pragma unroll
    for (int off = 32; off; off >>= 1) acc += __shfl_down(acc, off);
    const int lane = tid & 63, wid = tid >> 6;
    if (lane == 0) s_red[wid] = acc;
    __syncthreads();
    if (tid == 0) {
        float bs = s_red[0] + s_red[1] + s_red[2] + s_red[3];   // >= 0
        // Hierarchical fence-free deterministic reduce. All communicated data
        // rides INSIDE u64 atomics (packed [sum : count]), so no fences and no
        // plain-store visibility assumptions. Integer adds commute -> bitwise
        // deterministic. 8 group counters avoid R6's same-address serialization.
        unsigned long long iv = (unsigned long long)(long long)((double)bs * SCALE);
        const int g = bid & (RGROUPS - 1);
        unsigned long long old =
            atomicAdd(&ctrs[1 + g], (iv << CNT1_BITS) | 1ull);
        if ((old & ((1ull << CNT1_BITS) - 1ull)) == (unsigned long long)(GSIZE - 1)) {
            unsigned long long gtot = (old >> CNT1_BITS) + iv;   // this group's 64 block sums
            unsigned long long old2 =
                atomicAdd(&ctrs[0], (gtot << CNT2_BITS) | 1ull);
            if ((old2 & ((1ull << CNT2_BITS) - 1ull)) == (unsigned long long)(RGROUPS - 1)) {
                unsigned long long tot = (old2 >> CNT2_BITS) + gtot;  // all 512 blocks
                out[0] = (float)((double)tot * (1.0 / (SCALE * (double)NS)));
            }
        }
    }
}

// ---------------- fallback: direct evaluation (R3, validated) ----------------
__global__ __launch_bounds__(THREADS, 4) void direct_stage1(
    const float* __restrict__ u0p, const float* __restrict__ u1p,
    const float* __restrict__ u2p, const float* __restrict__ u3p,
    const float* __restrict__ sW1, const float* __restrict__ sb1,
    const float* __restrict__ sW2, const float* __restrict__ sb2,
    const float* __restrict__ jW1, const float* __restrict__ jb1,
    const float* __restrict__ jW2, const float* __restrict__ jb2,
    float* __restrict__ out)
{
    __shared__ __align__(16) float s_w[64][12];
    __shared__ float s_swv[2];
    __shared__ float s_red[THREADS / 64];

    const int bid = blockIdx.x;
    const int seg = bid / FBPS;
    const int chunk = bid - seg * FBPS;
    const int tid = threadIdx.x;

    const int ca  = (seg < 2) ? 0 : 1;
    const int pp  = 1 - ca;
    const int kv  = (seg < 2) ? 2 : 1;
    const int kd2 = 3 - kv;
    const float sign  = (seg & 1) ? -1.0f : 1.0f;
    const float alpha = (seg == 0) ? 3.0f : ((seg == 3) ? -1.0f : 1.0f);
    const float beta  = (seg <  2) ? -5.0f : ((seg == 2) ? -3.0f : -7.0f);
    const float TL = 2.885390081777927f;

    if (tid < 64) {
        const int j = tid;
        float sw1c = sW1[ca * 64 + j], jw1c = jW1[ca * 64 + j];
        float sw1p = sW1[pp * 64 + j], jw1p = jW1[pp * 64 + j];
        s_w[j][0] = sw1c * TL * sign;
        s_w[j][1] = jw1c * TL * sign;
        s_w[j][2] = sb1[j] * TL;
        s_w[j][3] = jb1[j] * TL;
        s_w[j][4] = 4.0f * sw1p * sW2[j * 3 + 0];
        s_w[j][5] = 4.0f * jw1p * jW2[j * 3 + 0];
        s_w[j][6] = 4.0f * sw1p * sW2[j * 3 + kd2];
        s_w[j][7] = 4.0f * jw1p * jW2[j * 3 + kd2];
        s_w[j][8] = sW2[j * 3 + kv];
        s_w[j][9] = jW2[j * 3 + kv];
    }
    __syncthreads();
    if (tid < 2) {
        float s = 0.0f;
        for (int j = 0; j < 64; ++j) s += s_w[j][8 + tid];
        s_swv[tid] = s + (tid ? jb2[kv] : sb2[kv]);
    }
    __syncthreads();

    const float* up = (seg == 0) ? u0p : (seg == 1) ? u1p : (seg == 2) ? u2p : u3p;
    const float4* up4 = (const float4*)up;
    const int base = chunk * (FSPB / 4) + tid;
    const float4 a4 = up4[base];
    const float4 b4 = up4[base + THREADS];
    const float uu[FILP] = {a4.x, a4.y, a4.z, a4.w, b4.x, b4.y, b4.z, b4.w};

    float Vgs[FILP], D0s[FILP], D2s[FILP], Vgj[FILP], D0j[FILP], D2j[FILP];
    #pragma unroll
    for (int s = 0; s < FILP; ++s) {
        Vgs[s] = 0.0f; D0s[s] = 0.0f; D2s[s] = 0.0f;
        Vgj[s] = 0.0f; D0j[s] = 0.0f; D2j[s] = 0.0f;
    }

    #pragma unroll 2
    for (int j = 0; j < 64; ++j) {
        const float4 A = *(const float4*)&s_w[j][0];
        const float4 B = *(const float4*)&s_w[j][4];
        const v2f   wv = *(const v2f*)&s_w[j][8];
        #pragma unroll
        for (int s = 0; s < FILP; ++s) {
            float ps = fmaf(A.x, uu[s], A.z);
            float Es = __builtin_amdgcn_exp2f(ps);
            float gs = __builtin_amdgcn_rcpf(Es + 1.0f);
            float ts = fmaf(-gs, gs, gs);
            Vgs[s] = fmaf(gs, wv.x, Vgs[s]);
            D0s[s] = fmaf(ts, B.x, D0s[s]);
            D2s[s] = fmaf(ts, B.z, D2s[s]);
            float pj = fmaf(A.y, uu[s], A.w);
            float Ej = __builtin_amdgcn_exp2f(pj);
            float gj = __builtin_amdgcn_rcpf(Ej + 1.0f);
            float tj = fmaf(-gj, gj, gj);
            Vgj[s] = fmaf(gj, wv.y, Vgj[s]);
            D0j[s] = fmaf(tj, B.y, D0j[s]);
            D2j[s] = fmaf(tj, B.w, D2j[s]);
        }
    }

    const float swv_s = s_swv[0], swv_j = s_swv[1];
    float acc = 0.0f;
    #pragma unroll
    for (int s = 0; s < FILP; ++s) {
        const float u = uu[s];
        float r = __builtin_amdgcn_sqrtf(fmaf(u, u, 1e-12f));
        float inv_r = __builtin_amdgcn_rcpf(r);
        float rcb = fmaxf(fmaf(-2.0f, r, 1.0f), 0.0f);
        float rc = rcb * rcb;
        float rl = __builtin_amdgcn_exp2f(0.66666666666666663f * __builtin_amdgcn_logf(r));
        float rcrl = rc * rl;
        float rcrlm1 = rcrl * inv_r;
        float q = u * inv_r;
        float bcv = fmaf(-u, u, 1.0f);
        float wgt = fminf(40.0f * u, 1.0f);
        float VS = fmaf(-2.0f, Vgs[s], swv_s);
        float VJ = fmaf(-2.0f, Vgj[s], swv_j);
        float dphi1 = fmaf(D2s[s], q, D0s[s]) * rcrl
                    + bcv * fmaf(D2j[s], u, D0j[s]);
        float corr = VJ * bcv + VS * rcrlm1;
        float val = fmaf(alpha, dphi1, beta * corr);
        acc = fmaf(val * val, wgt, acc);
    }

    #pragma unroll
    for (int off = 32; off; off >>= 1) acc += __shfl_down(acc, off);
    const int lane = tid & 63, wid = tid >> 6;
    if (lane == 0) s_red[wid] = acc;
    __syncthreads();
    if (tid == 0) {
        float bs = s_red[0] + s_red[1] + s_red[2] + s_red[3];
        atomicAdd(out, bs * (1.0f / (float)NS));
    }
}

extern "C" void kernel_launch(void* const* d_in, const int* in_sizes, int n_in,
                              void* d_out, int out_size, void* d_ws, size_t ws_size,
                              hipStream_t stream) {
    const float* u_y1  = (const float*)d_in[0];
    const float* u_ym1 = (const float*)d_in[1];
    const float* u_x1  = (const float*)d_in[2];
    const float* u_xm1 = (const float*)d_in[3];
    const float* sW1 = (const float*)d_in[4];
    const float* sb1 = (const float*)d_in[5];
    const float* sW2 = (const float*)d_in[6];
    const float* sb2 = (const float*)d_in[7];
    const float* jW1 = (const float*)d_in[8];
    const float* jb1 = (const float*)d_in[9];
    const float* jW2 = (const float*)d_in[10];
    const float* jb2 = (const float*)d_in[11];
    float* out = (float*)d_out;

    if (ws_size >= WS_NEED) {
        unsigned long long* ctrs = (unsigned long long*)d_ws;  // [0]=level2, [1..8]=groups
        float* tab = (float*)((char*)d_ws + 256);              // 4*TABSTRIDE floats
        build_tab<<<BGRID, THREADS, 0, stream>>>(
            sW1, sb1, sW2, sb2, jW1, jb1, jW2, jb2, tab, ctrs);
        eval_main<<<MGRID, THREADS, 0, stream>>>(
            u_y1, u_ym1, u_x1, u_xm1, tab, ctrs, out);
    } else {
        hipMemsetAsync(d_out, 0, sizeof(float), stream);
        direct_stage1<<<FGRID, THREADS, 0, stream>>>(
            u_y1, u_ym1, u_x1, u_xm1, sW1, sb1, sW2, sb2, jW1, jb1, jW2, jb2,
            out);
    }
}

// Round 9
// 15.385 us; speedup vs baseline: 1.3008x; 1.3008x over previous
//
#include <hip/hip_runtime.h>

// Problem constants (match reference)
#define NS (1 << 20)          // samples per segment
#define THREADS 256
#define TABN 4096             // interp cells per segment (nodes 0..TABN)
#define TABSTRIDE 4160        // floats per segment table slot (float4-aligned)

// build kernel: 64 nodes per block, 4-way j-split per node
#define BNODES 64
#define BBPS 65               // ceil((TABN+1)/BNODES)
#define BGRID (4 * BBPS)      // 260

// eval kernel geometry
#define MILP 32
#define MSPB (THREADS * MILP)             // 8192 samples per block
#define MBPS (NS / MSPB)                  // 128 blocks per seg
#define MGRID (4 * MBPS)                  // 512

// hierarchical fence-free reduce: 16 groups of 32 blocks,
// each counter in its OWN 256B slot -> distinct TCC channels (parallel RMW).
#define RGROUPS 16
#define GSIZE (MGRID / RGROUPS)           // 32
#define CNT1_BITS 6                       // count field for 32 arrivals
#define CNT2_BITS 5                       // count field for 16 arrivals
#define CPAD 32                           // u64 per counter slot = 256 bytes

// fallback (direct) kernel geometry
#define FILP 8
#define FSPB (THREADS * FILP)
#define FBPS (NS / FSPB)                  // 512
#define FGRID (4 * FBPS)                  // 2048

#define SCALE 262144.0        // 2^18 fixed-point scale for deterministic i64 reduce
#define TAB_BYTES ((size_t)(4 * TABSTRIDE * sizeof(float)))
#define CTR_BYTES ((size_t)8192)
#define WS_NEED (CTR_BYTES + TAB_BYTES)

typedef float v2f __attribute__((ext_vector_type(2)));

// Per-segment parameterization (validated on HW rounds 1/3/4/5/6/7/8, absmax 0.0):
// seg 0: u_y1  (jump_y, +1): val = 3*dphi1 - 5*corr
// seg 1: u_ym1 (jump_y, -1): val = 1*dphi1 - 5*corr
// seg 2: u_x1  (jump_x, +1): val = 1*dphi1 - 3*corr
// seg 3: u_xm1 (jump_x, -1): val = -1*dphi1 - 7*corr

// ---------------- table build: G_seg at nodes i/TABN, i in [0, TABN] ----------------
__global__ __launch_bounds__(THREADS) void build_tab(
    const float* __restrict__ sW1, const float* __restrict__ sb1,
    const float* __restrict__ sW2, const float* __restrict__ sb2,
    const float* __restrict__ jW1, const float* __restrict__ jb1,
    const float* __restrict__ jW2, const float* __restrict__ jb2,
    float* __restrict__ tab, unsigned long long* __restrict__ ctrs)
{
    __shared__ __align__(16) float s_w[64][12];
    __shared__ float s_swv[2];

    const int bid = blockIdx.x;
    const int seg = bid / BBPS;
    const int blk = bid - seg * BBPS;
    const int tid = threadIdx.x;

    // Zero the reduce counters with AGENT-scope atomic stores (visible to
    // eval's memory-side atomic RMWs). One 256B-padded slot per counter.
    if (bid == 0 && tid < 1 + RGROUPS)
        __hip_atomic_store(&ctrs[tid * CPAD], 0ull, __ATOMIC_RELAXED, __HIP_MEMORY_SCOPE_AGENT);

    const int ca  = (seg < 2) ? 0 : 1;
    const int pp  = 1 - ca;
    const int kv  = (seg < 2) ? 2 : 1;
    const int kd2 = 3 - kv;
    const float sign  = (seg & 1) ? -1.0f : 1.0f;
    const float alpha = (seg == 0) ? 3.0f : ((seg == 3) ? -1.0f : 1.0f);
    const float beta  = (seg <  2) ? -5.0f : ((seg == 2) ? -3.0f : -7.0f);
    const float TL = 2.885390081777927f;             // 2*log2(e)

    if (tid < 64) {
        const int j = tid;
        float sw1c = sW1[ca * 64 + j], jw1c = jW1[ca * 64 + j];
        float sw1p = sW1[pp * 64 + j], jw1p = jW1[pp * 64 + j];
        s_w[j][0] = sw1c * TL * sign;                // pre = wc*u + bb (sign folded)
        s_w[j][1] = jw1c * TL * sign;
        s_w[j][2] = sb1[j] * TL;
        s_w[j][3] = jb1[j] * TL;
        s_w[j][4] = 4.0f * sw1p * sW2[j * 3 + 0];    // x4: tp = t/4
        s_w[j][5] = 4.0f * jw1p * jW2[j * 3 + 0];
        s_w[j][6] = 4.0f * sw1p * sW2[j * 3 + kd2];
        s_w[j][7] = 4.0f * jw1p * jW2[j * 3 + kd2];
        s_w[j][8] = sW2[j * 3 + kv];
        s_w[j][9] = jW2[j * 3 + kv];
    }
    __syncthreads();
    if (tid < 2) {
        float s = 0.0f;
        for (int j = 0; j < 64; ++j) s += s_w[j][8 + tid];
        s_swv[tid] = s + (tid ? jb2[kv] : sb2[kv]);  // V = swv - 2*sum(g*wv)
    }
    __syncthreads();

    // 4 threads per node: part p handles j in [16p, 16p+16)
    const int part = tid & 3;
    const int node = blk * BNODES + (tid >> 2);
    const float u = (float)node * (1.0f / TABN);

    float Vgs = 0.0f, D0s = 0.0f, D2s = 0.0f, Vgj = 0.0f, D0j = 0.0f, D2j = 0.0f;
    #pragma unroll 4
    for (int jj = 0; jj < 16; ++jj) {
        const int j = (part << 4) | jj;
        const float4 A = *(const float4*)&s_w[j][0];
        const float4 B = *(const float4*)&s_w[j][4];
        const v2f   wv = *(const v2f*)&s_w[j][8];
        float ps = fmaf(A.x, u, A.z);
        float Es = __builtin_amdgcn_exp2f(ps);
        float gs = __builtin_amdgcn_rcpf(Es + 1.0f);
        float ts = fmaf(-gs, gs, gs);
        Vgs = fmaf(gs, wv.x, Vgs);
        D0s = fmaf(ts, B.x, D0s);
        D2s = fmaf(ts, B.z, D2s);
        float pj = fmaf(A.y, u, A.w);
        float Ej = __builtin_amdgcn_exp2f(pj);
        float gj = __builtin_amdgcn_rcpf(Ej + 1.0f);
        float tj = fmaf(-gj, gj, gj);
        Vgj = fmaf(gj, wv.y, Vgj);
        D0j = fmaf(tj, B.y, D0j);
        D2j = fmaf(tj, B.w, D2j);
    }
    // combine the 4 j-parts (lanes 4k..4k+3 hold the same node)
    #pragma unroll
    for (int m = 1; m <= 2; m <<= 1) {
        Vgs += __shfl_xor(Vgs, m); D0s += __shfl_xor(D0s, m); D2s += __shfl_xor(D2s, m);
        Vgj += __shfl_xor(Vgj, m); D0j += __shfl_xor(D0j, m); D2j += __shfl_xor(D2j, m);
    }

    float r = __builtin_amdgcn_sqrtf(fmaf(u, u, 1e-12f));
    float inv_r = __builtin_amdgcn_rcpf(r);
    float rcb = fmaxf(fmaf(-2.0f, r, 1.0f), 0.0f);   // max(1 - r/0.5, 0)
    float rc = rcb * rcb;
    float rl = __builtin_amdgcn_exp2f(0.66666666666666663f * __builtin_amdgcn_logf(r));
    float rcrl = rc * rl;                            // rc * r^(2/3)
    float rcrlm1 = rcrl * inv_r;                     // rc * r^(2/3 - 1)
    float q = u * inv_r;
    float bcv = fmaf(-u, u, 1.0f);
    float wgt = fminf(40.0f * u, 1.0f);
    float VS = fmaf(-2.0f, Vgs, s_swv[0]);
    float VJ = fmaf(-2.0f, Vgj, s_swv[1]);
    float dphi1 = fmaf(D2s, q, D0s) * rcrl + bcv * fmaf(D2j, u, D0j);
    float corr = VJ * bcv + VS * rcrlm1;
    float val = fmaf(alpha, dphi1, beta * corr);
    float G = val * val * wgt;                       // >= 0 always

    if (part == 0 && node <= TABN) tab[seg * TABSTRIDE + node] = G;
}

// ---------------- main: LDS table + interp + channel-parallel fence-free reduce ----------------
__global__ __launch_bounds__(THREADS) void eval_main(
    const float* __restrict__ u0p, const float* __restrict__ u1p,
    const float* __restrict__ u2p, const float* __restrict__ u3p,
    const float* __restrict__ tab, unsigned long long* __restrict__ ctrs,
    float* __restrict__ out)
{
    __shared__ __align__(16) float s_tab[TABN + 4];   // 16.4 KiB
    __shared__ float s_red[THREADS / 64];

    const int bid = blockIdx.x;
    const int seg = bid >> 7;                      // MBPS = 128
    const int chunk = bid & 127;
    const int tid = threadIdx.x;

    // stage this segment's table (4096 floats as float4 + boundary node 4096)
    {
        const float4* src = (const float4*)(tab + seg * TABSTRIDE);
        float4* dst = (float4*)s_tab;
        #pragma unroll
        for (int t = 0; t < 4; ++t)
            dst[t * THREADS + tid] = src[t * THREADS + tid];
        if (tid == 0) s_tab[TABN] = tab[seg * TABSTRIDE + TABN];
    }
    __syncthreads();

    const float* up = (seg == 0) ? u0p : (seg == 1) ? u1p : (seg == 2) ? u2p : u3p;
    const float4* up4 = (const float4*)up;

    float acc = 0.0f;
    #pragma unroll
    for (int t = 0; t < MILP / 4; ++t) {
        float4 u4 = up4[chunk * (MSPB / 4) + t * THREADS + tid];
        float us[4] = {u4.x, u4.y, u4.z, u4.w};
        #pragma unroll
        for (int s = 0; s < 4; ++s) {
            float fidx = us[s] * (float)TABN;
            int i = (int)fidx;
            i = (i < TABN - 1) ? i : (TABN - 1);
            float f = fidx - (float)i;
            float T0 = s_tab[i];          // pair compiles to ds_read2_b32
            float T1 = s_tab[i + 1];
            acc += fmaf(f, T1 - T0, T0);
        }
    }

    #pragma unroll
    for (int off = 32; off; off >>= 1) acc += __shfl_down(acc, off);
    const int lane = tid & 63, wid = tid >> 6;
    if (lane == 0) s_red[wid] = acc;
    __syncthreads();
    if (tid == 0) {
        float bs = s_red[0] + s_red[1] + s_red[2] + s_red[3];   // >= 0
        // Fence-free deterministic reduce; counters padded 256B apart so the
        // 16 group counters live on distinct cache lines / TCC channels and
        // their RMW streams proceed in parallel (R8 post-mortem fix).
        unsigned long long iv = (unsigned long long)(long long)((double)bs * SCALE);
        const int g = bid & (RGROUPS - 1);
        unsigned long long old =
            atomicAdd(&ctrs[(1 + g) * CPAD], (iv << CNT1_BITS) | 1ull);
        if ((old & ((1ull << CNT1_BITS) - 1ull)) == (unsigned long long)(GSIZE - 1)) {
            unsigned long long gtot = (old >> CNT1_BITS) + iv;   // this group's 32 block sums
            unsigned long long old2 =
                atomicAdd(&ctrs[0], (gtot << CNT2_BITS) | 1ull);
            if ((old2 & ((1ull << CNT2_BITS) - 1ull)) == (unsigned long long)(RGROUPS - 1)) {
                unsigned long long tot = (old2 >> CNT2_BITS) + gtot;  // all 512 blocks
                out[0] = (float)((double)tot * (1.0 / (SCALE * (double)NS)));
            }
        }
    }
}

// ---------------- fallback: direct evaluation (R3, validated) ----------------
__global__ __launch_bounds__(THREADS, 4) void direct_stage1(
    const float* __restrict__ u0p, const float* __restrict__ u1p,
    const float* __restrict__ u2p, const float* __restrict__ u3p,
    const float* __restrict__ sW1, const float* __restrict__ sb1,
    const float* __restrict__ sW2, const float* __restrict__ sb2,
    const float* __restrict__ jW1, const float* __restrict__ jb1,
    const float* __restrict__ jW2, const float* __restrict__ jb2,
    float* __restrict__ out)
{
    __shared__ __align__(16) float s_w[64][12];
    __shared__ float s_swv[2];
    __shared__ float s_red[THREADS / 64];

    const int bid = blockIdx.x;
    const int seg = bid / FBPS;
    const int chunk = bid - seg * FBPS;
    const int tid = threadIdx.x;

    const int ca  = (seg < 2) ? 0 : 1;
    const int pp  = 1 - ca;
    const int kv  = (seg < 2) ? 2 : 1;
    const int kd2 = 3 - kv;
    const float sign  = (seg & 1) ? -1.0f : 1.0f;
    const float alpha = (seg == 0) ? 3.0f : ((seg == 3) ? -1.0f : 1.0f);
    const float beta  = (seg <  2) ? -5.0f : ((seg == 2) ? -3.0f : -7.0f);
    const float TL = 2.885390081777927f;

    if (tid < 64) {
        const int j = tid;
        float sw1c = sW1[ca * 64 + j], jw1c = jW1[ca * 64 + j];
        float sw1p = sW1[pp * 64 + j], jw1p = jW1[pp * 64 + j];
        s_w[j][0] = sw1c * TL * sign;
        s_w[j][1] = jw1c * TL * sign;
        s_w[j][2] = sb1[j] * TL;
        s_w[j][3] = jb1[j] * TL;
        s_w[j][4] = 4.0f * sw1p * sW2[j * 3 + 0];
        s_w[j][5] = 4.0f * jw1p * jW2[j * 3 + 0];
        s_w[j][6] = 4.0f * sw1p * sW2[j * 3 + kd2];
        s_w[j][7] = 4.0f * jw1p * jW2[j * 3 + kd2];
        s_w[j][8] = sW2[j * 3 + kv];
        s_w[j][9] = jW2[j * 3 + kv];
    }
    __syncthreads();
    if (tid < 2) {
        float s = 0.0f;
        for (int j = 0; j < 64; ++j) s += s_w[j][8 + tid];
        s_swv[tid] = s + (tid ? jb2[kv] : sb2[kv]);
    }
    __syncthreads();

    const float* up = (seg == 0) ? u0p : (seg == 1) ? u1p : (seg == 2) ? u2p : u3p;
    const float4* up4 = (const float4*)up;
    const int base = chunk * (FSPB / 4) + tid;
    const float4 a4 = up4[base];
    const float4 b4 = up4[base + THREADS];
    const float uu[FILP] = {a4.x, a4.y, a4.z, a4.w, b4.x, b4.y, b4.z, b4.w};

    float Vgs[FILP], D0s[FILP], D2s[FILP], Vgj[FILP], D0j[FILP], D2j[FILP];
    #pragma unroll
    for (int s = 0; s < FILP; ++s) {
        Vgs[s] = 0.0f; D0s[s] = 0.0f; D2s[s] = 0.0f;
        Vgj[s] = 0.0f; D0j[s] = 0.0f; D2j[s] = 0.0f;
    }

    #pragma unroll 2
    for (int j = 0; j < 64; ++j) {
        const float4 A = *(const float4*)&s_w[j][0];
        const float4 B = *(const float4*)&s_w[j][4];
        const v2f   wv = *(const v2f*)&s_w[j][8];
        #pragma unroll
        for (int s = 0; s < FILP; ++s) {
            float ps = fmaf(A.x, uu[s], A.z);
            float Es = __builtin_amdgcn_exp2f(ps);
            float gs = __builtin_amdgcn_rcpf(Es + 1.0f);
            float ts = fmaf(-gs, gs, gs);
            Vgs[s] = fmaf(gs, wv.x, Vgs[s]);
            D0s[s] = fmaf(ts, B.x, D0s[s]);
            D2s[s] = fmaf(ts, B.z, D2s[s]);
            float pj = fmaf(A.y, uu[s], A.w);
            float Ej = __builtin_amdgcn_exp2f(pj);
            float gj = __builtin_amdgcn_rcpf(Ej + 1.0f);
            float tj = fmaf(-gj, gj, gj);
            Vgj[s] = fmaf(gj, wv.y, Vgj[s]);
            D0j[s] = fmaf(tj, B.y, D0j[s]);
            D2j[s] = fmaf(tj, B.w, D2j[s]);
        }
    }

    const float swv_s = s_swv[0], swv_j = s_swv[1];
    float acc = 0.0f;
    #pragma unroll
    for (int s = 0; s < FILP; ++s) {
        const float u = uu[s];
        float r = __builtin_amdgcn_sqrtf(fmaf(u, u, 1e-12f));
        float inv_r = __builtin_amdgcn_rcpf(r);
        float rcb = fmaxf(fmaf(-2.0f, r, 1.0f), 0.0f);
        float rc = rcb * rcb;
        float rl = __builtin_amdgcn_exp2f(0.66666666666666663f * __builtin_amdgcn_logf(r));
        float rcrl = rc * rl;
        float rcrlm1 = rcrl * inv_r;
        float q = u * inv_r;
        float bcv = fmaf(-u, u, 1.0f);
        float wgt = fminf(40.0f * u, 1.0f);
        float VS = fmaf(-2.0f, Vgs[s], swv_s);
        float VJ = fmaf(-2.0f, Vgj[s], swv_j);
        float dphi1 = fmaf(D2s[s], q, D0s[s]) * rcrl
                    + bcv * fmaf(D2j[s], u, D0j[s]);
        float corr = VJ * bcv + VS * rcrlm1;
        float val = fmaf(alpha, dphi1, beta * corr);
        acc = fmaf(val * val, wgt, acc);
    }

    #pragma unroll
    for (int off = 32; off; off >>= 1) acc += __shfl_down(acc, off);
    const int lane = tid & 63, wid = tid >> 6;
    if (lane == 0) s_red[wid] = acc;
    __syncthreads();
    if (tid == 0) {
        float bs = s_red[0] + s_red[1] + s_red[2] + s_red[3];
        atomicAdd(out, bs * (1.0f / (float)NS));
    }
}

extern "C" void kernel_launch(void* const* d_in, const int* in_sizes, int n_in,
                              void* d_out, int out_size, void* d_ws, size_t ws_size,
                              hipStream_t stream) {
    const float* u_y1  = (const float*)d_in[0];
    const float* u_ym1 = (const float*)d_in[1];
    const float* u_x1  = (const float*)d_in[2];
    const float* u_xm1 = (const float*)d_in[3];
    const float* sW1 = (const float*)d_in[4];
    const float* sb1 = (const float*)d_in[5];
    const float* sW2 = (const float*)d_in[6];
    const float* sb2 = (const float*)d_in[7];
    const float* jW1 = (const float*)d_in[8];
    const float* jb1 = (const float*)d_in[9];
    const float* jW2 = (const float*)d_in[10];
    const float* jb2 = (const float*)d_in[11];
    float* out = (float*)d_out;

    if (ws_size >= WS_NEED) {
        unsigned long long* ctrs = (unsigned long long*)d_ws;  // padded: [0]=lvl2, [(1+g)*CPAD]=groups
        float* tab = (float*)((char*)d_ws + CTR_BYTES);        // 4*TABSTRIDE floats
        build_tab<<<BGRID, THREADS, 0, stream>>>(
            sW1, sb1, sW2, sb2, jW1, jb1, jW2, jb2, tab, ctrs);
        eval_main<<<MGRID, THREADS, 0, stream>>>(
            u_y1, u_ym1, u_x1, u_xm1, tab, ctrs, out);
    } else {
        hipMemsetAsync(d_out, 0, sizeof(float), stream);
        direct_stage1<<<FGRID, THREADS, 0, stream>>>(
            u_y1, u_ym1, u_x1, u_xm1, sW1, sb1, sW2, sb2, jW1, jb1, jW2, jb2,
            out);
    }
}